// Round 1
// baseline (2255.490 us; speedup 1.0000x reference)
//
#include <hip/hip_runtime.h>
#include <math.h>

// Problem constants (fixed by setup_inputs)
#define BATCH 32
#define CH    64
#define HH    96
#define WW    96
#define NT    64   // number of reference types

// conv tiling
#define TW_ 32          // tile width
#define TH_ 8           // tile rows
#define CI_CHUNK 16     // in-channel chunk staged in LDS

// d_ws layout: [0, 8192) bytes = x_feat sums (2048 floats); f1 at +8192
// needs ws_size >= 8192 + 32*64*96*96*4 = 75,505,664 bytes

__global__ void zero_f(float* p, int n) {
    int i = blockIdx.x * 256 + threadIdx.x;
    if (i < n) p[i] = 0.f;
}

// POOL=0: write f1 = relu(bn(conv(src)))  (NCHW)
// POOL=1: accumulate spatial sums of relu(bn(conv(src))) into dst[b*64+o]
template <int POOL>
__global__ __launch_bounds__(256, 2)
void conv_bn_relu(const float* __restrict__ src, const float* __restrict__ wgt,
                  const float* __restrict__ gg, const float* __restrict__ bb,
                  const float* __restrict__ mm, const float* __restrict__ vv_,
                  float* __restrict__ dst) {
    __shared__ float s_in[CI_CHUNK][TH_ + 2][TW_ + 2];  // input strip w/ halo
    __shared__ float s_w[CI_CHUNK][9][64];              // weights [i][tap][o]
    __shared__ float s_s[64], s_t[64];                  // folded BN scale/shift

    const int tx = threadIdx.x;
    const int b  = blockIdx.z;
    const int h0 = blockIdx.y * TH_;
    const int w0 = blockIdx.x * TW_;

    if (tx < 64) {
        float inv = rsqrtf(vv_[tx] + 1e-5f);
        s_s[tx] = gg[tx] * inv;
        s_t[tx] = bb[tx] - mm[tx] * gg[tx] * inv;
    }

    float acc[64];
#pragma unroll
    for (int o = 0; o < 64; ++o) acc[o] = 0.f;

    const int wl = tx & 31;   // local col 0..31
    const int rl = tx >> 5;   // local row 0..7

    for (int ci0 = 0; ci0 < CH; ci0 += CI_CHUNK) {
        __syncthreads();  // protect previous chunk's LDS reads
        // ---- stage input strip (with zero-padded halo) ----
        for (int idx = tx; idx < CI_CHUNK * (TH_ + 2) * (TW_ + 2); idx += 256) {
            int i   = idx / ((TH_ + 2) * (TW_ + 2));
            int rem = idx % ((TH_ + 2) * (TW_ + 2));
            int r   = rem / (TW_ + 2);
            int cc  = rem % (TW_ + 2);
            int gh = h0 + r - 1, gw = w0 + cc - 1;
            float val = 0.f;
            if (gh >= 0 && gh < HH && gw >= 0 && gw < WW)
                val = src[((b * CH + ci0 + i) * HH + gh) * WW + gw];
            s_in[i][r][cc] = val;
        }
        // ---- stage weights: s_w[i][tap][o] (o contiguous for float4 bcast) ----
        for (int idx = tx; idx < CI_CHUNK * 9 * 64; idx += 256) {
            int i   = idx / 576;
            int rem = idx % 576;
            int tap = rem >> 6;
            int o   = rem & 63;
            s_w[i][tap][o] = wgt[(o * CH + ci0 + i) * 9 + tap];
        }
        __syncthreads();

#pragma unroll 1
        for (int i = 0; i < CI_CHUNK; ++i) {
            float vv[9];
#pragma unroll
            for (int dh = 0; dh < 3; ++dh)
#pragma unroll
                for (int dw = 0; dw < 3; ++dw)
                    vv[dh * 3 + dw] = s_in[i][rl + dh][wl + dw];
#pragma unroll
            for (int tap = 0; tap < 9; ++tap) {
                const float4* wp = (const float4*)&s_w[i][tap][0];
#pragma unroll
                for (int og = 0; og < 16; ++og) {
                    float4 wq = wp[og];  // wave-broadcast, conflict-free
                    acc[og * 4 + 0] = fmaf(vv[tap], wq.x, acc[og * 4 + 0]);
                    acc[og * 4 + 1] = fmaf(vv[tap], wq.y, acc[og * 4 + 1]);
                    acc[og * 4 + 2] = fmaf(vv[tap], wq.z, acc[og * 4 + 2]);
                    acc[og * 4 + 3] = fmaf(vv[tap], wq.w, acc[og * 4 + 3]);
                }
            }
        }
    }

    const int h = h0 + rl, w = w0 + wl;
    if (POOL) {
        const int lane = tx & 63;
#pragma unroll 1
        for (int o = 0; o < 64; ++o) {
            float y = fmaxf(fmaf(acc[o], s_s[o], s_t[o]), 0.f);
#pragma unroll
            for (int off = 32; off > 0; off >>= 1)
                y += __shfl_xor(y, off, 64);
            if (lane == 0) atomicAdd(&dst[b * 64 + o], y);
        }
    } else {
#pragma unroll 1
        for (int o = 0; o < 64; ++o) {
            float y = fmaxf(fmaf(acc[o], s_s[o], s_t[o]), 0.f);
            dst[((b * CH + o) * HH + h) * WW + w] = y;
        }
    }
}

// Fused head: x_feat -> MLP -> softmax/loss -> EMA ref_new -> weighted ref -> out
__global__ __launch_bounds__(256)
void head_kernel(const float* __restrict__ xfs, const float* __restrict__ rx,
                 const int* __restrict__ ty_g,
                 const float* __restrict__ w1, const float* __restrict__ b1,
                 const float* __restrict__ w2, const float* __restrict__ b2,
                 const float* __restrict__ rproj, float* __restrict__ out) {
    __shared__ float xf[BATCH][64];
    __shared__ float hb[BATCH][128];
    __shared__ float lg[BATCH][NT];
    __shared__ float tw[BATCH][NT];
    __shared__ float rnew[NT][64];
    __shared__ int   ty[BATCH];
    __shared__ float lossb[BATCH];

    const int tx = threadIdx.x;

    for (int i = tx; i < BATCH * 64; i += 256) xf[i >> 6][i & 63] = xfs[i] * (1.f / 9216.f);
    if (tx < BATCH) ty[tx] = ty_g[tx];
    __syncthreads();

    // MLP layer 1: [32,64] @ [64,128] + b1, ReLU
    for (int idx = tx; idx < BATCH * 128; idx += 256) {
        int b = idx >> 7, j = idx & 127;
        float s = b1[j];
        for (int c = 0; c < 64; ++c) s = fmaf(xf[b][c], w1[c * 128 + j], s);
        hb[b][j] = fmaxf(s, 0.f);
    }
    __syncthreads();

    // MLP layer 2: [32,128] @ [128,64] + b2
    for (int idx = tx; idx < BATCH * NT; idx += 256) {
        int b = idx >> 6, t = idx & 63;
        float s = b2[t];
        for (int j = 0; j < 128; ++j) s = fmaf(hb[b][j], w2[j * 64 + t], s);
        lg[b][t] = s;
    }
    __syncthreads();

    // softmax (T=1) + cross-entropy per row
    if (tx < BATCH) {
        int b = tx;
        float mx = -1e30f;
        for (int t = 0; t < NT; ++t) mx = fmaxf(mx, lg[b][t]);
        float sum = 0.f;
        for (int t = 0; t < NT; ++t) sum += expf(lg[b][t] - mx);
        float inv = 1.f / sum;
        for (int t = 0; t < NT; ++t) tw[b][t] = expf(lg[b][t] - mx) * inv;
        lossb[b] = -(lg[b][ty[b]] - mx - logf(sum));
    }
    __syncthreads();

    // sequential EMA scatter (iterative form == reference closed form)
    for (int idx = tx; idx < NT * 64; idx += 256) {
        int t = idx >> 6, c = idx & 63;
        float r = rproj[idx];
        for (int i = 0; i < BATCH; ++i)
            if (ty[i] == t) r = 0.99f * r + (1.0f - 0.99f) * rx[i * 64 + c];
        rnew[t][c] = r;
        out[2049 + idx] = r;  // ref_new output
    }
    __syncthreads();

    // weighted reference + residual
    for (int idx = tx; idx < BATCH * 64; idx += 256) {
        int b = idx >> 6, c = idx & 63;
        float s = 0.f;
        for (int t = 0; t < NT; ++t) s = fmaf(tw[b][t], rnew[t][c], s);
        out[idx] = s + rx[idx];
    }
    if (tx == 0) {
        float s = 0.f;
        for (int b = 0; b < BATCH; ++b) s += lossb[b];
        out[2048] = s * (1.f / 32.f);
    }
}

extern "C" void kernel_launch(void* const* d_in, const int* in_sizes, int n_in,
                              void* d_out, int out_size, void* d_ws, size_t ws_size,
                              hipStream_t stream) {
    const float* x    = (const float*)d_in[0];
    const float* rx   = (const float*)d_in[1];
    const int*   ty   = (const int*)d_in[2];
    const float* c1w  = (const float*)d_in[3];
    const float* bn1g = (const float*)d_in[4];
    const float* bn1b = (const float*)d_in[5];
    const float* bn1m = (const float*)d_in[6];
    const float* bn1v = (const float*)d_in[7];
    const float* c2w  = (const float*)d_in[8];
    const float* bn2g = (const float*)d_in[9];
    const float* bn2b = (const float*)d_in[10];
    const float* bn2m = (const float*)d_in[11];
    const float* bn2v = (const float*)d_in[12];
    const float* w1   = (const float*)d_in[13];
    const float* b1   = (const float*)d_in[14];
    const float* w2   = (const float*)d_in[15];
    const float* b2   = (const float*)d_in[16];
    const float* rpj  = (const float*)d_in[17];

    float* xfs = (float*)d_ws;                       // 2048 floats
    float* f1  = (float*)((char*)d_ws + 8192);       // 32*64*96*96 floats
    float* out = (float*)d_out;

    zero_f<<<8, 256, 0, stream>>>(xfs, BATCH * 64);

    dim3 grid(WW / TW_, HH / TH_, BATCH);  // (3, 12, 32)
    conv_bn_relu<0><<<grid, 256, 0, stream>>>(x,  c1w, bn1g, bn1b, bn1m, bn1v, f1);
    conv_bn_relu<1><<<grid, 256, 0, stream>>>(f1, c2w, bn2g, bn2b, bn2m, bn2v, xfs);

    head_kernel<<<1, 256, 0, stream>>>(xfs, rx, ty, w1, b1, w2, b2, rpj, out);
}

// Round 2
// 1118.497 us; speedup vs baseline: 2.0165x; 2.0165x over previous
//
#include <hip/hip_runtime.h>
#include <math.h>

// Problem constants (fixed by setup_inputs)
#define BATCH 32
#define CH    64
#define HH    96
#define WW    96
#define NT    64   // number of reference types

// conv tiling
#define TW_ 32          // tile width
#define TH_ 8           // tile rows
#define CI_CHUNK 16     // in-channel chunk staged in LDS

// d_ws layout (bytes):
//   [0,        8192)        x_feat sums (2048 floats)
//   [8192,     155648)      wt1: conv1 weights transposed [ci][tap][o]
//   [155648,   303104)      wt2: conv2 weights transposed
//   [303104,   75800576)    f1: 32*64*96*96 floats

__global__ void zero_f(float* p, int n) {
    int i = blockIdx.x * 256 + threadIdx.x;
    if (i < n) p[i] = 0.f;
}

// wt[(ci*9+tap)*64 + o] = w[(o*64+ci)*9+tap]
__global__ void transpose_w(const float* __restrict__ w, float* __restrict__ wt) {
    int idx = blockIdx.x * 256 + threadIdx.x;
    if (idx < CH * CH * 9) {
        int o = idx / 576;
        int rem = idx % 576;
        int ci = rem / 9;
        int tap = rem % 9;
        wt[(ci * 9 + tap) * 64 + o] = w[idx];
    }
}

// POOL=0: write f1 = relu(bn(conv(src)))  (NCHW)
// POOL=1: accumulate spatial sums of relu(bn(conv(src))) into dst[b*64+o]
// wt: transposed weights [ci][tap][o] — read with wave-uniform addresses so the
// compiler scalarizes to s_load and the FMA takes the weight in its SGPR slot.
template <int POOL>
__global__ __launch_bounds__(256, 4)
void conv_bn_relu(const float* __restrict__ src, const float* __restrict__ wt,
                  const float* __restrict__ gg, const float* __restrict__ bb,
                  const float* __restrict__ mm, const float* __restrict__ vv_,
                  float* __restrict__ dst) {
    __shared__ float s_in[CI_CHUNK][TH_ + 2][TW_ + 2];  // input strip w/ halo
    __shared__ float s_s[64], s_t[64];                  // folded BN scale/shift

    const int tx = threadIdx.x;
    const int b  = blockIdx.z;
    const int h0 = blockIdx.y * TH_;
    const int w0 = blockIdx.x * TW_;

    if (tx < 64) {
        float inv = rsqrtf(vv_[tx] + 1e-5f);
        s_s[tx] = gg[tx] * inv;
        s_t[tx] = bb[tx] - mm[tx] * gg[tx] * inv;
    }

    float acc[64];
#pragma unroll
    for (int o = 0; o < 64; ++o) acc[o] = 0.f;

    const int wl = tx & 31;   // local col 0..31
    const int rl = tx >> 5;   // local row 0..7

    for (int ci0 = 0; ci0 < CH; ci0 += CI_CHUNK) {
        __syncthreads();  // protect previous chunk's LDS reads (and s_s/s_t init)
        // ---- stage input strip (with zero-padded halo) ----
        for (int idx = tx; idx < CI_CHUNK * (TH_ + 2) * (TW_ + 2); idx += 256) {
            int i   = idx / ((TH_ + 2) * (TW_ + 2));
            int rem = idx % ((TH_ + 2) * (TW_ + 2));
            int r   = rem / (TW_ + 2);
            int cc  = rem % (TW_ + 2);
            int gh = h0 + r - 1, gw = w0 + cc - 1;
            float val = 0.f;
            if (gh >= 0 && gh < HH && gw >= 0 && gw < WW)
                val = src[((b * CH + ci0 + i) * HH + gh) * WW + gw];
            s_in[i][r][cc] = val;
        }
        __syncthreads();

#pragma unroll 1
        for (int i = 0; i < CI_CHUNK; ++i) {
            float vv[9];
#pragma unroll
            for (int dh = 0; dh < 3; ++dh)
#pragma unroll
                for (int dw = 0; dw < 3; ++dw)
                    vv[dh * 3 + dw] = s_in[i][rl + dh][wl + dw];

            const float* wrow = wt + (ci0 + i) * 9 * 64;
#pragma unroll
            for (int tap = 0; tap < 9; ++tap) {
#pragma unroll
                for (int og = 0; og < 16; ++og) {
                    // uniform address -> s_load; weight rides the SGPR operand
                    float4 wq = *(const float4*)(wrow + tap * 64 + og * 4);
                    acc[og * 4 + 0] = fmaf(vv[tap], wq.x, acc[og * 4 + 0]);
                    acc[og * 4 + 1] = fmaf(vv[tap], wq.y, acc[og * 4 + 1]);
                    acc[og * 4 + 2] = fmaf(vv[tap], wq.z, acc[og * 4 + 2]);
                    acc[og * 4 + 3] = fmaf(vv[tap], wq.w, acc[og * 4 + 3]);
                }
            }
        }
    }

    const int h = h0 + rl, w = w0 + wl;
    if (POOL) {
        const int lane = tx & 63;
#pragma unroll
        for (int o = 0; o < 64; ++o) {
            float y = fmaxf(fmaf(acc[o], s_s[o], s_t[o]), 0.f);
#pragma unroll
            for (int off = 32; off > 0; off >>= 1)
                y += __shfl_xor(y, off, 64);
            if (lane == 0) atomicAdd(&dst[b * 64 + o], y);
        }
    } else {
#pragma unroll
        for (int o = 0; o < 64; ++o) {
            float y = fmaxf(fmaf(acc[o], s_s[o], s_t[o]), 0.f);
            dst[((b * CH + o) * HH + h) * WW + w] = y;
        }
    }
}

// Fused head: x_feat -> MLP -> softmax/loss -> EMA ref_new -> weighted ref -> out
__global__ __launch_bounds__(256)
void head_kernel(const float* __restrict__ xfs, const float* __restrict__ rx,
                 const int* __restrict__ ty_g,
                 const float* __restrict__ w1, const float* __restrict__ b1,
                 const float* __restrict__ w2, const float* __restrict__ b2,
                 const float* __restrict__ rproj, float* __restrict__ out) {
    __shared__ float xf[BATCH][64];
    __shared__ float hb[BATCH][128];
    __shared__ float lg[BATCH][NT];
    __shared__ float tw[BATCH][NT];
    __shared__ float rnew[NT][64];
    __shared__ int   ty[BATCH];
    __shared__ float lossb[BATCH];

    const int tx = threadIdx.x;

    for (int i = tx; i < BATCH * 64; i += 256) xf[i >> 6][i & 63] = xfs[i] * (1.f / 9216.f);
    if (tx < BATCH) ty[tx] = ty_g[tx];
    __syncthreads();

    // MLP layer 1: [32,64] @ [64,128] + b1, ReLU
    for (int idx = tx; idx < BATCH * 128; idx += 256) {
        int b = idx >> 7, j = idx & 127;
        float s = b1[j];
        for (int c = 0; c < 64; ++c) s = fmaf(xf[b][c], w1[c * 128 + j], s);
        hb[b][j] = fmaxf(s, 0.f);
    }
    __syncthreads();

    // MLP layer 2: [32,128] @ [128,64] + b2
    for (int idx = tx; idx < BATCH * NT; idx += 256) {
        int b = idx >> 6, t = idx & 63;
        float s = b2[t];
        for (int j = 0; j < 128; ++j) s = fmaf(hb[b][j], w2[j * 64 + t], s);
        lg[b][t] = s;
    }
    __syncthreads();

    // softmax (T=1) + cross-entropy per row
    if (tx < BATCH) {
        int b = tx;
        float mx = -1e30f;
        for (int t = 0; t < NT; ++t) mx = fmaxf(mx, lg[b][t]);
        float sum = 0.f;
        for (int t = 0; t < NT; ++t) sum += expf(lg[b][t] - mx);
        float inv = 1.f / sum;
        for (int t = 0; t < NT; ++t) tw[b][t] = expf(lg[b][t] - mx) * inv;
        lossb[b] = -(lg[b][ty[b]] - mx - logf(sum));
    }
    __syncthreads();

    // sequential EMA scatter (iterative form == reference closed form)
    for (int idx = tx; idx < NT * 64; idx += 256) {
        int t = idx >> 6, c = idx & 63;
        float r = rproj[idx];
        for (int i = 0; i < BATCH; ++i)
            if (ty[i] == t) r = 0.99f * r + (1.0f - 0.99f) * rx[i * 64 + c];
        rnew[t][c] = r;
        out[2049 + idx] = r;  // ref_new output
    }
    __syncthreads();

    // weighted reference + residual
    for (int idx = tx; idx < BATCH * 64; idx += 256) {
        int b = idx >> 6, c = idx & 63;
        float s = 0.f;
        for (int t = 0; t < NT; ++t) s = fmaf(tw[b][t], rnew[t][c], s);
        out[idx] = s + rx[idx];
    }
    if (tx == 0) {
        float s = 0.f;
        for (int b = 0; b < BATCH; ++b) s += lossb[b];
        out[2048] = s * (1.f / 32.f);
    }
}

extern "C" void kernel_launch(void* const* d_in, const int* in_sizes, int n_in,
                              void* d_out, int out_size, void* d_ws, size_t ws_size,
                              hipStream_t stream) {
    const float* x    = (const float*)d_in[0];
    const float* rx   = (const float*)d_in[1];
    const int*   ty   = (const int*)d_in[2];
    const float* c1w  = (const float*)d_in[3];
    const float* bn1g = (const float*)d_in[4];
    const float* bn1b = (const float*)d_in[5];
    const float* bn1m = (const float*)d_in[6];
    const float* bn1v = (const float*)d_in[7];
    const float* c2w  = (const float*)d_in[8];
    const float* bn2g = (const float*)d_in[9];
    const float* bn2b = (const float*)d_in[10];
    const float* bn2m = (const float*)d_in[11];
    const float* bn2v = (const float*)d_in[12];
    const float* w1   = (const float*)d_in[13];
    const float* b1   = (const float*)d_in[14];
    const float* w2   = (const float*)d_in[15];
    const float* b2   = (const float*)d_in[16];
    const float* rpj  = (const float*)d_in[17];

    float* xfs = (float*)d_ws;                        // 2048 floats
    float* wt1 = (float*)((char*)d_ws + 8192);        // 64*9*64 floats
    float* wt2 = (float*)((char*)d_ws + 155648);      // 64*9*64 floats
    float* f1  = (float*)((char*)d_ws + 303104);      // 32*64*96*96 floats
    float* out = (float*)d_out;

    zero_f<<<8, 256, 0, stream>>>(xfs, BATCH * 64);
    transpose_w<<<(CH * CH * 9 + 255) / 256, 256, 0, stream>>>(c1w, wt1);
    transpose_w<<<(CH * CH * 9 + 255) / 256, 256, 0, stream>>>(c2w, wt2);

    dim3 grid(WW / TW_, HH / TH_, BATCH);  // (3, 12, 32)
    conv_bn_relu<0><<<grid, 256, 0, stream>>>(x,  wt1, bn1g, bn1b, bn1m, bn1v, f1);
    conv_bn_relu<1><<<grid, 256, 0, stream>>>(f1, wt2, bn2g, bn2b, bn2m, bn2v, xfs);

    head_kernel<<<1, 256, 0, stream>>>(xfs, rx, ty, w1, b1, w2, b2, rpj, out);
}

// Round 3
// 378.315 us; speedup vs baseline: 5.9619x; 2.9565x over previous
//
#include <hip/hip_runtime.h>
#include <math.h>

#define BATCH 32
#define CH    64
#define HH    96
#define WW    96
#define NT    64

using short8  = __attribute__((ext_vector_type(8))) short;
using f32x16  = __attribute__((ext_vector_type(16))) float;

// d_ws layout (bytes):
//   [0, 8192)                xfs: x_feat sums (2048 f32)
//   [8192, 81920)            A1: conv1 weights bf16 [o][k=tap*64+ci]  (64*576*2)
//   [81920, 155648)          A2: conv2 weights bf16
//   [155648, 37904384)       x_t: [b][h][w][ci] bf16
//   [37904384, 75653120)     f1t: [b][h][w][o]  bf16

__device__ __forceinline__ unsigned short b16(float f) {
    unsigned int u = __builtin_bit_cast(unsigned int, f);
    unsigned int r = (u + 0x7FFFu + ((u >> 16) & 1u)) >> 16;
    return (unsigned short)r;
}

__global__ void zero_f(float* p, int n) {
    int i = blockIdx.x * 256 + threadIdx.x;
    if (i < n) p[i] = 0.f;
}

// w[o][ci][3][3] f32 -> At[o][tap*64+ci] bf16
__global__ void prep_a(const float* __restrict__ w, unsigned short* __restrict__ At) {
    int idx = blockIdx.x * 256 + threadIdx.x;
    if (idx < CH * 576) {
        int o = idx / 576, k = idx % 576;
        int tap = k >> 6, ci = k & 63;
        At[o * 576 + k] = b16(w[(o * 64 + ci) * 9 + tap]);
    }
}

// x[b][ci][h][w] f32 -> xt[b][h][w][ci] bf16
__global__ __launch_bounds__(256)
void prep_x(const float* __restrict__ x, unsigned short* __restrict__ xt) {
    const int h = blockIdx.x, b = blockIdx.y, tx = threadIdx.x;
#pragma unroll
    for (int i = 0; i < 6; ++i) {
        int idx = i * 256 + tx;          // 1536 = 96 w * 16 cig
        int cig = idx / 96;
        int w = idx - cig * 96;
        ushort4 u;
        u.x = b16(x[((b * 64 + cig * 4 + 0) * 96 + h) * 96 + w]);
        u.y = b16(x[((b * 64 + cig * 4 + 1) * 96 + h) * 96 + w]);
        u.z = b16(x[((b * 64 + cig * 4 + 2) * 96 + h) * 96 + w]);
        u.w = b16(x[((b * 64 + cig * 4 + 3) * 96 + h) * 96 + w]);
        *(ushort4*)(xt + ((size_t)(b * 96 + h) * 96 + w) * 64 + cig * 4) = u;
    }
}

// Implicit-GEMM conv + BN + ReLU.  POOL=0: write f1t bf16 [h][w][o].
// POOL=1: spatial-sum into xfs[b*64+o] via shfl-reduce + atomicAdd.
// LDS tile [4 rows][96 cols][64 ci] bf16, 16B-slot XOR-swizzle: slot = col*8 + (cib ^ (col&7)).
template <int POOL>
__global__ __launch_bounds__(256, 2)
void conv_mfma(const unsigned short* __restrict__ xt, const unsigned short* __restrict__ At,
               const float* __restrict__ gg, const float* __restrict__ bb,
               const float* __restrict__ mm, const float* __restrict__ vv_,
               unsigned short* __restrict__ f1t, float* __restrict__ xfs) {
    __shared__ char smem[49152];
    __shared__ float s_s[64], s_t[64];

    const int tx = threadIdx.x;
    const int ry = blockIdx.x, b = blockIdx.y;
    const int r0 = ry * 2;
    const int wv = tx >> 6, l = tx & 63;
    const int mt = wv & 1, rh = wv >> 1;     // wave = (m-tile, row-within-pair)
    const int kb = l >> 5, ln = l & 31;

    if (tx < 64) {
        float inv = rsqrtf(vv_[tx] + 1e-5f);
        s_s[tx] = gg[tx] * inv;
        s_t[tx] = bb[tx] - mm[tx] * gg[tx] * inv;
    }

    // ---- A fragments: whole K in VGPRs (36 x short8 = 144 VGPR) ----
    const int o_ = mt * 32 + ln;
    const unsigned short* ap = At + o_ * 576 + kb * 8;
    short8 af[36];
#pragma unroll
    for (int s = 0; s < 36; ++s) af[s] = *(const short8*)(ap + s * 16);

    // ---- stage input rows r0-1 .. r0+2 into LDS rows 0..3 (wave wv -> row wv) ----
    {
        const int row = r0 - 1 + wv;
        if (row >= 0 && row < 96) {
            const unsigned short* src = xt + ((size_t)b * 96 + row) * 96 * 64;
#pragma unroll
            for (int i = 0; i < 12; ++i) {
                int m_ = i * 64 + l;                       // 16B chunk id: col*8+cib
                ushort8_t_dummy: ;
                short8 v = *(const short8*)(src + m_ * 8); // coalesced
                int slot = m_ ^ ((m_ >> 3) & 7);           // XOR swizzle
                *(short8*)(smem + wv * 12288 + slot * 16) = v;
            }
        } else {
            short8 z = {};
#pragma unroll
            for (int i = 0; i < 12; ++i) {
                int m_ = i * 64 + l;
                *(short8*)(smem + wv * 12288 + m_ * 16) = z;
            }
        }
    }
    __syncthreads();

    // ---- per-lane B addressing: colb/ekq/msk per (nt, dw) ----
    int colb[3][3], ekq[3][3];
    bool msk0, msk2;
#pragma unroll
    for (int nt = 0; nt < 3; ++nt)
#pragma unroll
        for (int dw = 0; dw < 3; ++dw) {
            int cc = nt * 32 + ln + dw - 1;
            int ccc = cc < 0 ? 0 : (cc > 95 ? 95 : cc);
            colb[nt][dw] = rh * 12288 + ccc * 128;
            ekq[nt][dw] = (((ccc & 7) ^ kb) << 4);
        }
    msk0 = (ln == 0);    // nt=0,dw=0 -> cc=-1
    msk2 = (ln == 31);   // nt=2,dw=2 -> cc=96

    f32x16 acc[3] = {};

    // ---- K-loop: 9 taps x 4 ci-steps, 3 n-tiles; pure ds_read_b128 + MFMA ----
#pragma unroll
    for (int tap = 0; tap < 9; ++tap) {
        const int dh = tap / 3, dw = tap % 3;
#pragma unroll
        for (int t = 0; t < 4; ++t) {
            const int s = tap * 4 + t;
#pragma unroll
            for (int nt = 0; nt < 3; ++nt) {
                int ba = colb[nt][dw] + ((t << 5) ^ ekq[nt][dw]);
                short8 bf = *(const short8*)(smem + dh * 12288 + ba);
                if (nt == 0 && dw == 0) bf = msk0 ? (short8){} : bf;
                if (nt == 2 && dw == 2) bf = msk2 ? (short8){} : bf;
                acc[nt] = __builtin_amdgcn_mfma_f32_32x32x16_bf16(af[s], bf, acc[nt], 0, 0, 0);
            }
        }
    }

    // ---- epilogue ----
    const int r = r0 + rh;
    if (POOL == 0) {
        unsigned short* orow = f1t + ((size_t)b * 96 + r) * 96 * 64;
#pragma unroll
        for (int nt = 0; nt < 3; ++nt) {
#pragma unroll
            for (int q = 0; q < 16; ++q) {
                int o = mt * 32 + (q & 3) + 8 * (q >> 2) + 4 * kb;   // m101 C/D row map
                float y = fmaxf(fmaf(acc[nt][q], s_s[o], s_t[o]), 0.f);
                orow[(nt * 32 + ln) * 64 + o] = b16(y);
            }
        }
    } else {
#pragma unroll
        for (int q = 0; q < 16; ++q) {
            int o = mt * 32 + (q & 3) + 8 * (q >> 2) + 4 * kb;
            float ss = s_s[o], tt = s_t[o];
            float y = fmaxf(fmaf(acc[0][q], ss, tt), 0.f)
                    + fmaxf(fmaf(acc[1][q], ss, tt), 0.f)
                    + fmaxf(fmaf(acc[2][q], ss, tt), 0.f);
#pragma unroll
            for (int off = 1; off < 32; off <<= 1) y += __shfl_xor(y, off, 64);
            if (ln == 0) atomicAdd(&xfs[b * 64 + o], y);
        }
    }
}

// Fused head (unchanged from R2): x_feat -> MLP -> softmax/loss -> EMA -> out
__global__ __launch_bounds__(256)
void head_kernel(const float* __restrict__ xfs, const float* __restrict__ rx,
                 const int* __restrict__ ty_g,
                 const float* __restrict__ w1, const float* __restrict__ b1,
                 const float* __restrict__ w2, const float* __restrict__ b2,
                 const float* __restrict__ rproj, float* __restrict__ out) {
    __shared__ float xf[BATCH][64];
    __shared__ float hb[BATCH][128];
    __shared__ float lg[BATCH][NT];
    __shared__ float tw[BATCH][NT];
    __shared__ float rnew[NT][64];
    __shared__ int   ty[BATCH];
    __shared__ float lossb[BATCH];

    const int tx = threadIdx.x;

    for (int i = tx; i < BATCH * 64; i += 256) xf[i >> 6][i & 63] = xfs[i] * (1.f / 9216.f);
    if (tx < BATCH) ty[tx] = ty_g[tx];
    __syncthreads();

    for (int idx = tx; idx < BATCH * 128; idx += 256) {
        int b = idx >> 7, j = idx & 127;
        float s = b1[j];
        for (int c = 0; c < 64; ++c) s = fmaf(xf[b][c], w1[c * 128 + j], s);
        hb[b][j] = fmaxf(s, 0.f);
    }
    __syncthreads();

    for (int idx = tx; idx < BATCH * NT; idx += 256) {
        int b = idx >> 6, t = idx & 63;
        float s = b2[t];
        for (int j = 0; j < 128; ++j) s = fmaf(hb[b][j], w2[j * 64 + t], s);
        lg[b][t] = s;
    }
    __syncthreads();

    if (tx < BATCH) {
        int b = tx;
        float mx = -1e30f;
        for (int t = 0; t < NT; ++t) mx = fmaxf(mx, lg[b][t]);
        float sum = 0.f;
        for (int t = 0; t < NT; ++t) sum += expf(lg[b][t] - mx);
        float inv = 1.f / sum;
        for (int t = 0; t < NT; ++t) tw[b][t] = expf(lg[b][t] - mx) * inv;
        lossb[b] = -(lg[b][ty[b]] - mx - logf(sum));
    }
    __syncthreads();

    for (int idx = tx; idx < NT * 64; idx += 256) {
        int t = idx >> 6, c = idx & 63;
        float r = rproj[idx];
        for (int i = 0; i < BATCH; ++i)
            if (ty[i] == t) r = 0.99f * r + (1.0f - 0.99f) * rx[i * 64 + c];
        rnew[t][c] = r;
        out[2049 + idx] = r;
    }
    __syncthreads();

    for (int idx = tx; idx < BATCH * 64; idx += 256) {
        int b = idx >> 6, c = idx & 63;
        float s = 0.f;
        for (int t = 0; t < NT; ++t) s = fmaf(tw[b][t], rnew[t][c], s);
        out[idx] = s + rx[idx];
    }
    if (tx == 0) {
        float s = 0.f;
        for (int b = 0; b < BATCH; ++b) s += lossb[b];
        out[2048] = s * (1.f / 32.f);
    }
}

extern "C" void kernel_launch(void* const* d_in, const int* in_sizes, int n_in,
                              void* d_out, int out_size, void* d_ws, size_t ws_size,
                              hipStream_t stream) {
    const float* x    = (const float*)d_in[0];
    const float* rx   = (const float*)d_in[1];
    const int*   ty   = (const int*)d_in[2];
    const float* c1w  = (const float*)d_in[3];
    const float* bn1g = (const float*)d_in[4];
    const float* bn1b = (const float*)d_in[5];
    const float* bn1m = (const float*)d_in[6];
    const float* bn1v = (const float*)d_in[7];
    const float* c2w  = (const float*)d_in[8];
    const float* bn2g = (const float*)d_in[9];
    const float* bn2b = (const float*)d_in[10];
    const float* bn2m = (const float*)d_in[11];
    const float* bn2v = (const float*)d_in[12];
    const float* w1   = (const float*)d_in[13];
    const float* b1   = (const float*)d_in[14];
    const float* w2   = (const float*)d_in[15];
    const float* b2   = (const float*)d_in[16];
    const float* rpj  = (const float*)d_in[17];

    float*          xfs = (float*)d_ws;
    unsigned short* A1  = (unsigned short*)((char*)d_ws + 8192);
    unsigned short* A2  = (unsigned short*)((char*)d_ws + 81920);
    unsigned short* x_t = (unsigned short*)((char*)d_ws + 155648);
    unsigned short* f1t = (unsigned short*)((char*)d_ws + 37904384);
    float*          out = (float*)d_out;

    zero_f<<<8, 256, 0, stream>>>(xfs, BATCH * 64);
    prep_a<<<144, 256, 0, stream>>>(c1w, A1);
    prep_a<<<144, 256, 0, stream>>>(c2w, A2);
    prep_x<<<dim3(96, 32), 256, 0, stream>>>(x, x_t);

    dim3 grid(48, 32);  // (row-pairs, batch)
    conv_mfma<0><<<grid, 256, 0, stream>>>(x_t, A1, bn1g, bn1b, bn1m, bn1v, f1t, nullptr);
    conv_mfma<1><<<grid, 256, 0, stream>>>(f1t, A2, bn2g, bn2b, bn2m, bn2v, nullptr, xfs);

    head_kernel<<<1, 256, 0, stream>>>(xfs, rx, ty, w1, b1, w2, b2, rpj, out);
}

// Round 4
// 339.515 us; speedup vs baseline: 6.6433x; 1.1143x over previous
//
#include <hip/hip_runtime.h>
#include <math.h>

#define BATCH 32
#define CH    64
#define HH    96
#define WW    96
#define NT    64

using short8 = __attribute__((ext_vector_type(8))) short;
using f32x16 = __attribute__((ext_vector_type(16))) float;

// d_ws layout (bytes):
//   [0, 8192)            xfs: x_feat sums (2048 f32)
//   [8192, 8448)         zero page (64 f32) — zeroed every launch
//   [8448, 82176)        A1: conv1 weights packed [mt][c][tap][kb][o32][8k] bf16
//   [82176, 155904)      A2: conv2 weights packed
//   [155904, 37904640)   x_t: [b][h][w][ci64] bf16
//   [37904640, 75653376) f1t: [b][h][w][o64] bf16
#define WS_XFS   0
#define WS_ZERO  8192
#define WS_A1    8448
#define WS_A2    82176
#define WS_XT    155904
#define WS_F1T   37904640

__device__ __forceinline__ unsigned short b16(float f) {
    unsigned int u = __builtin_bit_cast(unsigned int, f);
    unsigned int r = (u + 0x7FFFu + ((u >> 16) & 1u)) >> 16;
    return (unsigned short)r;
}

__device__ __forceinline__ void gl_lds16(const void* g, void* l) {
    __builtin_amdgcn_global_load_lds(
        (const __attribute__((address_space(1))) unsigned int*)g,
        (__attribute__((address_space(3))) unsigned int*)l, 16, 0, 0);
}

// fused: A-pack for both convs (blocks 0..287) + zero xfs/zeropage (blocks 288+)
__global__ void prep_small(const float* __restrict__ c1w, const float* __restrict__ c2w,
                           char* __restrict__ ws) {
    const int bid = blockIdx.x, tx = threadIdx.x;
    if (bid < 288) {
        const float* w = bid < 144 ? c1w : c2w;
        unsigned short* At = (unsigned short*)(ws + (bid < 144 ? WS_A1 : WS_A2));
        int idx = (bid % 144) * 256 + tx;        // 0..36863
        int j = idx & 7, g1 = idx >> 3;
        int ga = g1 % 576, mc = g1 / 576;
        int c = mc & 3, mt = mc >> 1 >> 1;       // mc>>2
        int tap = ga >> 6, kb = (ga >> 5) & 1, ol = ga & 31;
        int o = mt * 32 + ol, ci = c * 16 + kb * 8 + j;
        At[idx] = b16(w[(o * 64 + ci) * 9 + tap]);
    } else {
        int i = (bid - 288) * 256 + tx;
        if (i < 2112) ((float*)ws)[i] = 0.f;     // xfs(2048) + zero page(64)
    }
}

// x[b][ci][h][w] f32 -> xt[b][h][w][ci] bf16 ; 1 output 16-B granule per thread
__global__ __launch_bounds__(256)
void prep_x(const float* __restrict__ x, unsigned short* __restrict__ xt) {
    int gid = blockIdx.x * 256 + threadIdx.x;    // cig-major: gid = cig*294912 + p
    int cig = gid / 294912;
    int p   = gid % 294912;                      // b*9216 + h*96 + w
    int b   = p / 9216;
    int hw  = p % 9216;
    const float* src = x + (size_t)(b * 64 + cig * 8) * 9216 + hw;
    ushort4 lo, hi;
    lo.x = b16(src[0 * 9216]); lo.y = b16(src[1 * 9216]);
    lo.z = b16(src[2 * 9216]); lo.w = b16(src[3 * 9216]);
    hi.x = b16(src[4 * 9216]); hi.y = b16(src[5 * 9216]);
    hi.z = b16(src[6 * 9216]); hi.w = b16(src[7 * 9216]);
    ushort4* dst = (ushort4*)(xt + (size_t)p * 64 + cig * 8);
    dst[0] = lo; dst[1] = hi;
}

// Implicit-GEMM conv + BN + ReLU. Block = 1 mt-half (32 och) x 4 output rows x 96 cols.
// 4 ci-chunks; per chunk: stage input [6rows][96col][16ci] (XOR-swizzled via source) +
// A-chunk [9tap][2kb][32o][8k] (linear), then 9 taps x {1 A-read, 3x(B-read + MFMA)}.
template <int POOL>
__global__ __launch_bounds__(256, 4)
void conv_mfma(const unsigned short* __restrict__ xt, const unsigned short* __restrict__ Aprep,
               const unsigned short* __restrict__ zerop,
               const float* __restrict__ gg, const float* __restrict__ bb,
               const float* __restrict__ mm, const float* __restrict__ vv_,
               unsigned short* __restrict__ f1t, float* __restrict__ xfs) {
    __shared__ char smem[28160];   // [0,18432) input ; [18432,27648) A ; [27648+] BN s/t
    float* s_s = (float*)(smem + 27648);
    float* s_t = (float*)(smem + 27904);

    const int tx = threadIdx.x;
    const int rg = blockIdx.x;            // 0..23 (4 output rows each)
    const int b  = blockIdx.y;
    const int mt = blockIdx.z;            // och half
    const int r0 = rg * 4;
    const int wv = tx >> 6, l = tx & 63;
    const int rh = wv;                    // wave = output row within group
    const int kb = l >> 5, ln = l & 31;

    if (tx < 64) {
        float inv = rsqrtf(vv_[tx] + 1e-5f);
        s_s[tx] = gg[tx] * inv;
        s_t[tx] = bb[tx] - mm[tx] * gg[tx] * inv;
    }

    // ---- per-lane staging source pointers (input: slot tx+256i holds logical sigma(slot)) ----
    const char* srcp0; const char* srcp1; const char* srcp2; const char* srcp3; const char* srcp4;
    {
        const char* sp[5];
#pragma unroll
        for (int i = 0; i < 5; ++i) {
            int g  = i * 256 + tx;
            int lg = g ^ ((g >> 3) & 7);          // involution: logical granule at slot g
            int row = lg / 192, s = lg % 192;
            int col = s >> 1, kb2 = s & 1;
            int grow = r0 - 1 + row;
            if (grow >= 0 && grow < 96)
                sp[i] = (const char*)(xt + ((size_t)(b * 96 + grow) * 96 + col) * 64 + kb2 * 8);
            else
                sp[i] = (const char*)zerop;
        }
        srcp0 = sp[0]; srcp1 = sp[1]; srcp2 = sp[2]; srcp3 = sp[3]; srcp4 = sp[4];
    }
    // A source: linear granules
    const char* abase = (const char*)Aprep + mt * 36864 + (size_t)tx * 16;

    // ---- per-lane B byte-offsets (within input tile) per (nt, dw) ----
    int boff[3][3];
#pragma unroll
    for (int nt = 0; nt < 3; ++nt)
#pragma unroll
        for (int dw = 0; dw < 3; ++dw) {
            int cc = nt * 32 + ln + dw - 1;
            int ccc = cc < 0 ? 0 : (cc > 95 ? 95 : cc);
            int s = ccc * 2 + kb;
            boff[nt][dw] = rh * 3072 + (s ^ ((s >> 3) & 7)) * 16;
        }
    const bool msk0 = (ln == 0), msk2 = (ln == 31);

    f32x16 acc[3] = {};

    for (int c = 0; c < 4; ++c) {
        __syncthreads();                           // prior chunk's reads done
        // stage input: 1152 granules (4.5 per thread)
        gl_lds16(srcp0 + c * 32, smem + 0     + wv * 1024);
        gl_lds16(srcp1 + c * 32, smem + 4096  + wv * 1024);
        gl_lds16(srcp2 + c * 32, smem + 8192  + wv * 1024);
        gl_lds16(srcp3 + c * 32, smem + 12288 + wv * 1024);
        if (tx < 128)
            gl_lds16(srcp4 + c * 32, smem + 16384 + wv * 1024);
        // stage A: 576 granules (2.25 per thread), linear
        gl_lds16(abase + c * 9216,        smem + 18432 + wv * 1024);
        gl_lds16(abase + c * 9216 + 4096, smem + 22528 + wv * 1024);
        if (tx < 64)
            gl_lds16(abase + c * 9216 + 8192, smem + 26624 + wv * 1024);
        __syncthreads();                           // vmcnt(0) drained by compiler

#pragma unroll
        for (int tap = 0; tap < 9; ++tap) {
            const int dh = tap / 3, dw = tap % 3;
            short8 af = *(const short8*)(smem + 18432 + tap * 1024 + kb * 512 + ln * 16);
#pragma unroll
            for (int nt = 0; nt < 3; ++nt) {
                short8 bf = *(const short8*)(smem + dh * 3072 + boff[nt][dw]);
                if (nt == 0 && dw == 0) bf = msk0 ? (short8){} : bf;
                if (nt == 2 && dw == 2) bf = msk2 ? (short8){} : bf;
                acc[nt] = __builtin_amdgcn_mfma_f32_32x32x16_bf16(af, bf, acc[nt], 0, 0, 0);
            }
        }
    }

    // ---- epilogue ----
    if (POOL == 0) {
        unsigned short* orow = f1t + (size_t)((b * 96 + r0 + rh) * 96) * 64;
#pragma unroll
        for (int nt = 0; nt < 3; ++nt) {
            const int col = nt * 32 + ln;
#pragma unroll
            for (int qh = 0; qh < 4; ++qh) {
                const int ob = 8 * qh + 4 * kb;        // o = mt*32 + ob + j
                uint2 pk;
                float y0 = fmaxf(fmaf(acc[nt][qh * 4 + 0], s_s[mt * 32 + ob + 0], s_t[mt * 32 + ob + 0]), 0.f);
                float y1 = fmaxf(fmaf(acc[nt][qh * 4 + 1], s_s[mt * 32 + ob + 1], s_t[mt * 32 + ob + 1]), 0.f);
                float y2 = fmaxf(fmaf(acc[nt][qh * 4 + 2], s_s[mt * 32 + ob + 2], s_t[mt * 32 + ob + 2]), 0.f);
                float y3 = fmaxf(fmaf(acc[nt][qh * 4 + 3], s_s[mt * 32 + ob + 3], s_t[mt * 32 + ob + 3]), 0.f);
                pk.x = (unsigned)b16(y0) | ((unsigned)b16(y1) << 16);
                pk.y = (unsigned)b16(y2) | ((unsigned)b16(y3) << 16);
                *(uint2*)(orow + (size_t)col * 64 + mt * 32 + ob) = pk;
            }
        }
    } else {
#pragma unroll
        for (int qh = 0; qh < 4; ++qh)
#pragma unroll
            for (int j = 0; j < 4; ++j) {
                const int o = mt * 32 + 8 * qh + 4 * kb + j;
                const float ss = s_s[o], tt = s_t[o];
                float y = fmaxf(fmaf(acc[0][qh * 4 + j], ss, tt), 0.f)
                        + fmaxf(fmaf(acc[1][qh * 4 + j], ss, tt), 0.f)
                        + fmaxf(fmaf(acc[2][qh * 4 + j], ss, tt), 0.f);
#pragma unroll
                for (int off = 1; off < 32; off <<= 1) y += __shfl_xor(y, off, 64);
                if (ln == 0) atomicAdd(&xfs[b * 64 + o], y);
            }
    }
}

// Fused head: x_feat -> MLP -> softmax/loss -> EMA ref_new -> weighted ref -> out
__global__ __launch_bounds__(1024)
void head_kernel(const float* __restrict__ xfs, const float* __restrict__ rx,
                 const int* __restrict__ ty_g,
                 const float* __restrict__ w1, const float* __restrict__ b1,
                 const float* __restrict__ w2, const float* __restrict__ b2,
                 const float* __restrict__ rproj, float* __restrict__ out) {
    __shared__ float xf[BATCH][64];     // reused as tw after MLP1
    __shared__ float hb[BATCH][128];
    __shared__ float lg[BATCH][NT];
    __shared__ float rnew[NT][64];
    __shared__ float rxs[BATCH * 64];
    __shared__ int   ty[BATCH];
    __shared__ float lossb[BATCH];

    const int tx = threadIdx.x;

    for (int i = tx; i < BATCH * 64; i += 1024) {
        xf[i >> 6][i & 63] = xfs[i] * (1.f / 9216.f);
        rxs[i] = rx[i];
    }
    if (tx < BATCH) ty[tx] = ty_g[tx];
    __syncthreads();

    // MLP1: [32,64]@[64,128]+b1, ReLU   (4096 outputs, 4/thread)
    {
        int idx = tx;
#pragma unroll
        for (int u = 0; u < 4; ++u, idx += 1024) {
            int bb_ = idx >> 7, j = idx & 127;
            float s = b1[j];
#pragma unroll 8
            for (int c = 0; c < 64; ++c) s = fmaf(xf[bb_][c], w1[c * 128 + j], s);
            hb[bb_][j] = fmaxf(s, 0.f);
        }
    }
    __syncthreads();

    // MLP2: [32,128]@[128,64]+b2   (2048 outputs, 2/thread)
    {
        int idx = tx;
#pragma unroll
        for (int u = 0; u < 2; ++u, idx += 1024) {
            int bb_ = idx >> 6, t = idx & 63;
            float s = b2[t];
#pragma unroll 8
            for (int j = 0; j < 128; ++j) s = fmaf(hb[bb_][j], w2[j * 64 + t], s);
            lg[bb_][t] = s;
        }
    }
    __syncthreads();

    float (*tw)[NT] = (float (*)[NT])xf;   // xf dead after MLP1
    if (tx < BATCH) {
        int b = tx;
        float mx = -1e30f;
        for (int t = 0; t < NT; ++t) mx = fmaxf(mx, lg[b][t]);
        float sum = 0.f;
        for (int t = 0; t < NT; ++t) sum += expf(lg[b][t] - mx);
        float inv = 1.f / sum;
        for (int t = 0; t < NT; ++t) tw[b][t] = expf(lg[b][t] - mx) * inv;
        lossb[b] = -(lg[b][ty[b]] - mx - logf(sum));
    }
    __syncthreads();

    // sequential EMA scatter (iterative == reference closed form)
    for (int idx = tx; idx < NT * 64; idx += 1024) {
        int t = idx >> 6, c = idx & 63;
        float r = rproj[idx];
#pragma unroll 8
        for (int i = 0; i < BATCH; ++i)
            if (ty[i] == t) r = 0.99f * r + 0.01f * rxs[i * 64 + c];
        rnew[t][c] = r;
        out[2049 + idx] = r;
    }
    __syncthreads();

    for (int idx = tx; idx < BATCH * 64; idx += 1024) {
        int b = idx >> 6, c = idx & 63;
        float s = 0.f;
#pragma unroll 8
        for (int t = 0; t < NT; ++t) s = fmaf(tw[b][t], rnew[t][c], s);
        out[idx] = s + rxs[idx];
    }
    if (tx == 0) {
        float s = 0.f;
        for (int b = 0; b < BATCH; ++b) s += lossb[b];
        out[2048] = s * (1.f / 32.f);
    }
}

extern "C" void kernel_launch(void* const* d_in, const int* in_sizes, int n_in,
                              void* d_out, int out_size, void* d_ws, size_t ws_size,
                              hipStream_t stream) {
    const float* x    = (const float*)d_in[0];
    const float* rx   = (const float*)d_in[1];
    const int*   ty   = (const int*)d_in[2];
    const float* c1w  = (const float*)d_in[3];
    const float* bn1g = (const float*)d_in[4];
    const float* bn1b = (const float*)d_in[5];
    const float* bn1m = (const float*)d_in[6];
    const float* bn1v = (const float*)d_in[7];
    const float* c2w  = (const float*)d_in[8];
    const float* bn2g = (const float*)d_in[9];
    const float* bn2b = (const float*)d_in[10];
    const float* bn2m = (const float*)d_in[11];
    const float* bn2v = (const float*)d_in[12];
    const float* w1   = (const float*)d_in[13];
    const float* b1   = (const float*)d_in[14];
    const float* w2   = (const float*)d_in[15];
    const float* b2   = (const float*)d_in[16];
    const float* rpj  = (const float*)d_in[17];

    char* ws = (char*)d_ws;
    float*          xfs = (float*)(ws + WS_XFS);
    unsigned short* zp  = (unsigned short*)(ws + WS_ZERO);
    unsigned short* A1  = (unsigned short*)(ws + WS_A1);
    unsigned short* A2  = (unsigned short*)(ws + WS_A2);
    unsigned short* x_t = (unsigned short*)(ws + WS_XT);
    unsigned short* f1t = (unsigned short*)(ws + WS_F1T);
    float*          out = (float*)d_out;

    prep_small<<<297, 256, 0, stream>>>(c1w, c2w, ws);
    prep_x<<<9216, 256, 0, stream>>>(x, x_t);

    dim3 grid(24, 32, 2);   // (row-groups, batch, och-half)
    conv_mfma<0><<<grid, 256, 0, stream>>>(x_t, A1, zp, bn1g, bn1b, bn1m, bn1v, f1t, nullptr);
    conv_mfma<1><<<grid, 256, 0, stream>>>(f1t, A2, zp, bn2g, bn2b, bn2m, bn2v, nullptr, xfs);

    head_kernel<<<1, 1024, 0, stream>>>(xfs, rx, ty, w1, b1, w2, b2, rpj, out);
}

// Round 6
// 305.184 us; speedup vs baseline: 7.3906x; 1.1125x over previous
//
#include <hip/hip_runtime.h>
#include <math.h>

#define BATCH 32
#define CH    64
#define HH    96
#define WW    96
#define NT    64

using short8 = __attribute__((ext_vector_type(8))) short;
using f32x16 = __attribute__((ext_vector_type(16))) float;

// d_ws layout (bytes):
//   [0, 8192)            xfs: x_feat sums (2048 f32)
//   [8192, 8448)         zero page (64 f32)
//   [8448, 82176)        A1: conv1 weights packed [mt][c][tap][kb][o32][8k] bf16
//   [82176, 155904)      A2: conv2 weights packed
//   [155904, 37904640)   x_t: 4 planes of [b][h][w][ci16] bf16 (plane = 9,437,184 B)
//   [37904640, 75653376) f1t: 4 planes of [b][h][w][o16]  bf16
#define WS_XFS   0
#define WS_ZERO  8192
#define WS_A1    8448
#define WS_A2    82176
#define WS_XT    155904
#define WS_F1T   37904640
#define PLANE    9437184   // bytes per ci-chunk plane

__device__ __forceinline__ unsigned short b16(float f) {
    unsigned int u = __builtin_bit_cast(unsigned int, f);
    unsigned int r = (u + 0x7FFFu + ((u >> 16) & 1u)) >> 16;
    return (unsigned short)r;
}

__device__ __forceinline__ void gl_lds16(const void* g, void* l) {
    __builtin_amdgcn_global_load_lds(
        (const __attribute__((address_space(1))) unsigned int*)g,
        (__attribute__((address_space(3))) unsigned int*)l, 16, 0, 0);
}

// fused: A-pack for both convs (blocks 0..287) + zero xfs/zeropage (blocks 288+)
__global__ void prep_small(const float* __restrict__ c1w, const float* __restrict__ c2w,
                           char* __restrict__ ws) {
    const int bid = blockIdx.x, tx = threadIdx.x;
    if (bid < 288) {
        const float* w = bid < 144 ? c1w : c2w;
        unsigned short* At = (unsigned short*)(ws + (bid < 144 ? WS_A1 : WS_A2));
        int idx = (bid % 144) * 256 + tx;        // 0..36863
        int j = idx & 7, g1 = idx >> 3;
        int ga = g1 % 576, mc = g1 / 576;        // mc = mt*4 + c
        int c = mc & 3, mt = mc >> 2;
        int tap = ga >> 6, kb = (ga >> 5) & 1, ol = ga & 31;
        int o = mt * 32 + ol, ci = c * 16 + kb * 8 + j;
        At[idx] = b16(w[(o * 64 + ci) * 9 + tap]);
    } else {
        int i = (bid - 288) * 256 + tx;
        if (i < 2112) ((float*)ws)[i] = 0.f;     // xfs(2048) + zero page(64)
    }
}

// x[b][ci][h][w] f32 -> x_t chunk-planes; 2 pixels x 8 ci per thread
__global__ __launch_bounds__(256)
void prep_x(const float* __restrict__ x, char* __restrict__ xt) {
    int gid = blockIdx.x * 256 + threadIdx.x;   // 8 cig * 147456 pixel-pairs
    int cig = gid / 147456;
    int pp  = gid % 147456;
    int p   = pp * 2;
    int b   = p / 9216;
    int hw  = p % 9216;
    const float* src = x + (size_t)(b * 64 + cig * 8) * 9216 + hw;
    float2 v0 = *(const float2*)(src + 0 * 9216);
    float2 v1 = *(const float2*)(src + 1 * 9216);
    float2 v2 = *(const float2*)(src + 2 * 9216);
    float2 v3 = *(const float2*)(src + 3 * 9216);
    float2 v4 = *(const float2*)(src + 4 * 9216);
    float2 v5 = *(const float2*)(src + 5 * 9216);
    float2 v6 = *(const float2*)(src + 6 * 9216);
    float2 v7 = *(const float2*)(src + 7 * 9216);
    int c = cig >> 1, kb2 = cig & 1;
    char* dst = xt + (size_t)c * PLANE + (size_t)p * 32 + kb2 * 16;
    ushort4 a0, a1, c0, c1;
    a0.x = b16(v0.x); a0.y = b16(v1.x); a0.z = b16(v2.x); a0.w = b16(v3.x);
    a1.x = b16(v4.x); a1.y = b16(v5.x); a1.z = b16(v6.x); a1.w = b16(v7.x);
    c0.x = b16(v0.y); c0.y = b16(v1.y); c0.z = b16(v2.y); c0.w = b16(v3.y);
    c1.x = b16(v4.y); c1.y = b16(v5.y); c1.z = b16(v6.y); c1.w = b16(v7.y);
    *(ushort4*)(dst)      = a0; *(ushort4*)(dst + 8)  = a1;
    *(ushort4*)(dst + 32) = c0; *(ushort4*)(dst + 40) = c1;
}

// Implicit-GEMM conv + BN + ReLU. Block = 512 thr (8 waves), 8 rows x 96 cols x 64 och.
// Wave = 1 output row, both och-halves. A-fragments in registers (L2-resident reads).
// LDS: input tile [10 rows][2 kb][96 col] 16-B granules = 30,720 B (conflict-free B-reads).
template <int POOL>
__global__ __launch_bounds__(512, 2)
void conv_mfma(const char* __restrict__ xt, const char* __restrict__ Aprep,
               const char* __restrict__ zerop,
               const float* __restrict__ gg, const float* __restrict__ bb,
               const float* __restrict__ mm, const float* __restrict__ vv_,
               char* __restrict__ f1t, float* __restrict__ xfs) {
    __shared__ char smem[31232];
    float* s_s = (float*)(smem + 30720);
    float* s_t = s_s + 64;

    const int tx = threadIdx.x;
    const int r0 = blockIdx.x * 8;
    const int b  = blockIdx.y;
    const int wv = tx >> 6, l = tx & 63;
    const int rh = wv;
    const int kb = l >> 5, ln = l & 31;

    if (tx < 64) {
        float inv = rsqrtf(vv_[tx] + 1e-5f);
        s_s[tx] = gg[tx] * inv;
        s_t[tx] = bb[tx] - mm[tx] * gg[tx] * inv;
    }

    // staging sources: slot i -> LDS granule-block q = wv + 8i (30 blocks of 64 granules)
    const char* sin[4];
    bool oob[4];
#pragma unroll
    for (int i = 0; i < 4; ++i) {
        int q = wv + 8 * i;
        int g = q * 64 + l;
        int row = g / 192, t = g % 192;
        int kb2 = t / 96, col = t % 96;
        int grow = r0 - 1 + row;
        oob[i] = (grow < 0) || (grow >= 96);
        int gr = oob[i] ? 0 : grow;
        sin[i] = xt + (size_t)((b * 96 + gr) * 96 + col) * 32 + kb2 * 16;
    }
    const char* abase = Aprep + (kb * 32 + ln) * 16;

    // B byte-offsets within a row: [nt][dw] (col clamped; masked at use)
    int bcol[3][3];
#pragma unroll
    for (int nt = 0; nt < 3; ++nt)
#pragma unroll
        for (int dw = 0; dw < 3; ++dw) {
            int cc = nt * 32 + ln + dw - 1;
            int ccc = cc < 0 ? 0 : (cc > 95 ? 95 : cc);
            bcol[nt][dw] = kb * 1536 + ccc * 16;
        }
    const bool msk0 = (ln == 0), msk2 = (ln == 31);

    f32x16 acc[2][3] = {};

#pragma unroll
    for (int c = 0; c < 4; ++c) {
        __syncthreads();                       // LDS safe to overwrite
        // ---- stage input chunk-plane slice (fully contiguous per wave-block) ----
#pragma unroll
        for (int i = 0; i < 4; ++i) {
            int q = wv + 8 * i;
            if (q < 30) {
                const char* s = oob[i] ? zerop : (sin[i] + (size_t)c * PLANE);
                gl_lds16(s, smem + q * 1024);
            }
        }
        // ---- A fragments into registers (L2-resident) ----
        short8 af[2][9];
#pragma unroll
        for (int mt = 0; mt < 2; ++mt)
#pragma unroll
            for (int tap = 0; tap < 9; ++tap)
                af[mt][tap] = *(const short8*)(abase + mt * 36864 + c * 9216 + tap * 1024);
        __syncthreads();                       // drains vmcnt -> LDS + af ready

        const char* brow = smem + rh * 3072;
#pragma unroll
        for (int tap = 0; tap < 9; ++tap) {
            const int dh = tap / 3, dw = tap % 3;
#pragma unroll
            for (int nt = 0; nt < 3; ++nt) {
                short8 bf = *(const short8*)(brow + dh * 3072 + bcol[nt][dw]);
                if (nt == 0 && dw == 0) bf = msk0 ? (short8){} : bf;
                if (nt == 2 && dw == 2) bf = msk2 ? (short8){} : bf;
                acc[0][nt] = __builtin_amdgcn_mfma_f32_32x32x16_bf16(af[0][tap], bf, acc[0][nt], 0, 0, 0);
                acc[1][nt] = __builtin_amdgcn_mfma_f32_32x32x16_bf16(af[1][tap], bf, acc[1][nt], 0, 0, 0);
            }
        }
    }

    // ---- epilogue ----
    const int r = r0 + rh;
    if (POOL == 0) {
#pragma unroll
        for (int nt = 0; nt < 3; ++nt) {
            int p = (b * 96 + r) * 96 + nt * 32 + ln;
            char* pb = f1t + (size_t)p * 32 + kb * 8;
#pragma unroll
            for (int mt = 0; mt < 2; ++mt)
#pragma unroll
                for (int qh = 0; qh < 4; ++qh) {
                    const int ob = mt * 32 + 8 * qh + 4 * kb;
                    float y0 = fmaxf(fmaf(acc[mt][nt][qh * 4 + 0], s_s[ob + 0], s_t[ob + 0]), 0.f);
                    float y1 = fmaxf(fmaf(acc[mt][nt][qh * 4 + 1], s_s[ob + 1], s_t[ob + 1]), 0.f);
                    float y2 = fmaxf(fmaf(acc[mt][nt][qh * 4 + 2], s_s[ob + 2], s_t[ob + 2]), 0.f);
                    float y3 = fmaxf(fmaf(acc[mt][nt][qh * 4 + 3], s_s[ob + 3], s_t[ob + 3]), 0.f);
                    uint2 pk;
                    pk.x = (unsigned)b16(y0) | ((unsigned)b16(y1) << 16);
                    pk.y = (unsigned)b16(y2) | ((unsigned)b16(y3) << 16);
                    *(uint2*)(pb + (size_t)(mt * 2 + (qh >> 1)) * PLANE + (qh & 1) * 16) = pk;
                }
        }
    } else {
#pragma unroll
        for (int mt = 0; mt < 2; ++mt)
#pragma unroll
            for (int qh = 0; qh < 4; ++qh)
#pragma unroll
                for (int j = 0; j < 4; ++j) {
                    const int o = mt * 32 + 8 * qh + 4 * kb + j;
                    const float ss = s_s[o], tt = s_t[o];
                    float y = fmaxf(fmaf(acc[mt][0][qh * 4 + j], ss, tt), 0.f)
                            + fmaxf(fmaf(acc[mt][1][qh * 4 + j], ss, tt), 0.f)
                            + fmaxf(fmaf(acc[mt][2][qh * 4 + j], ss, tt), 0.f);
#pragma unroll
                    for (int off = 1; off < 32; off <<= 1) y += __shfl_xor(y, off, 64);
                    if (ln == 0) atomicAdd(&xfs[b * 64 + o], y);
                }
    }
}

// Fused head: x_feat -> MLP -> softmax/loss -> EMA ref_new -> weighted ref -> out
__global__ __launch_bounds__(1024)
void head_kernel(const float* __restrict__ xfs, const float* __restrict__ rx,
                 const int* __restrict__ ty_g,
                 const float* __restrict__ w1, const float* __restrict__ b1,
                 const float* __restrict__ w2, const float* __restrict__ b2,
                 const float* __restrict__ rproj, float* __restrict__ out) {
    __shared__ float xf[BATCH][64];
    __shared__ float hb[BATCH][128];
    __shared__ float lg[BATCH][NT];
    __shared__ float rnew[NT][64];
    __shared__ float rxs[BATCH * 64];
    __shared__ int   ty[BATCH];
    __shared__ float lossb[BATCH];

    const int tx = threadIdx.x;

    for (int i = tx; i < BATCH * 64; i += 1024) {
        xf[i >> 6][i & 63] = xfs[i] * (1.f / 9216.f);
        rxs[i] = rx[i];
    }
    if (tx < BATCH) ty[tx] = ty_g[tx];
    __syncthreads();

    {
        int idx = tx;
#pragma unroll
        for (int u = 0; u < 4; ++u, idx += 1024) {
            int bb_ = idx >> 7, j = idx & 127;
            float s = b1[j];
#pragma unroll 8
            for (int c = 0; c < 64; ++c) s = fmaf(xf[bb_][c], w1[c * 128 + j], s);
            hb[bb_][j] = fmaxf(s, 0.f);
        }
    }
    __syncthreads();

    {
        int idx = tx;
#pragma unroll
        for (int u = 0; u < 2; ++u, idx += 1024) {
            int bb_ = idx >> 6, t = idx & 63;
            float s = b2[t];
#pragma unroll 8
            for (int j = 0; j < 128; ++j) s = fmaf(hb[bb_][j], w2[j * 64 + t], s);
            lg[bb_][t] = s;
        }
    }
    __syncthreads();

    float (*tw)[NT] = (float (*)[NT])xf;
    if (tx < BATCH) {
        int b = tx;
        float mx = -1e30f;
        for (int t = 0; t < NT; ++t) mx = fmaxf(mx, lg[b][t]);
        float sum = 0.f;
        for (int t = 0; t < NT; ++t) sum += expf(lg[b][t] - mx);
        float inv = 1.f / sum;
        for (int t = 0; t < NT; ++t) tw[b][t] = expf(lg[b][t] - mx) * inv;
        lossb[b] = -(lg[b][ty[b]] - mx - logf(sum));
    }
    __syncthreads();

    for (int idx = tx; idx < NT * 64; idx += 1024) {
        int t = idx >> 6, c = idx & 63;
        float r = rproj[idx];
#pragma unroll 8
        for (int i = 0; i < BATCH; ++i)
            if (ty[i] == t) r = 0.99f * r + 0.01f * rxs[i * 64 + c];
        rnew[t][c] = r;
        out[2049 + idx] = r;
    }
    __syncthreads();

    for (int idx = tx; idx < BATCH * 64; idx += 1024) {
        int b = idx >> 6, c = idx & 63;
        float s = 0.f;
#pragma unroll 8
        for (int t = 0; t < NT; ++t) s = fmaf(tw[b][t], rnew[t][c], s);
        out[idx] = s + rxs[idx];
    }
    if (tx == 0) {
        float s = 0.f;
        for (int b = 0; b < BATCH; ++b) s += lossb[b];
        out[2048] = s * (1.f / 32.f);
    }
}

extern "C" void kernel_launch(void* const* d_in, const int* in_sizes, int n_in,
                              void* d_out, int out_size, void* d_ws, size_t ws_size,
                              hipStream_t stream) {
    const float* x    = (const float*)d_in[0];
    const float* rx   = (const float*)d_in[1];
    const int*   ty   = (const int*)d_in[2];
    const float* c1w  = (const float*)d_in[3];
    const float* bn1g = (const float*)d_in[4];
    const float* bn1b = (const float*)d_in[5];
    const float* bn1m = (const float*)d_in[6];
    const float* bn1v = (const float*)d_in[7];
    const float* c2w  = (const float*)d_in[8];
    const float* bn2g = (const float*)d_in[9];
    const float* bn2b = (const float*)d_in[10];
    const float* bn2m = (const float*)d_in[11];
    const float* bn2v = (const float*)d_in[12];
    const float* w1   = (const float*)d_in[13];
    const float* b1   = (const float*)d_in[14];
    const float* w2   = (const float*)d_in[15];
    const float* b2   = (const float*)d_in[16];
    const float* rpj  = (const float*)d_in[17];

    char* ws = (char*)d_ws;
    float* xfs = (float*)(ws + WS_XFS);
    char*  zp  = ws + WS_ZERO;
    char*  A1  = ws + WS_A1;
    char*  A2  = ws + WS_A2;
    char*  x_t = ws + WS_XT;
    char*  f1t = ws + WS_F1T;
    float* out = (float*)d_out;

    prep_small<<<297, 256, 0, stream>>>(c1w, c2w, ws);
    prep_x<<<4608, 256, 0, stream>>>(x, x_t);

    dim3 grid(12, 32);   // (8-row groups, batch)
    conv_mfma<0><<<grid, 512, 0, stream>>>(x_t, A1, zp, bn1g, bn1b, bn1m, bn1v, f1t, nullptr);
    conv_mfma<1><<<grid, 512, 0, stream>>>(f1t, A2, zp, bn2g, bn2b, bn2m, bn2v, nullptr, xfs);

    head_kernel<<<1, 1024, 0, stream>>>(xfs, rx, ty, w1, b1, w2, b2, rpj, out);
}

// Round 8
// 288.553 us; speedup vs baseline: 7.8166x; 1.0576x over previous
//
#include <hip/hip_runtime.h>
#include <math.h>

#define BATCH 32
#define CH    64
#define HH    96
#define WW    96
#define NT    64

using short8 = __attribute__((ext_vector_type(8))) short;
using f32x16 = __attribute__((ext_vector_type(16))) float;

// d_ws layout (bytes):
//   [0, 8192)            xfs: x_feat sums (2048 f32)
//   [8192, 8448)         zero page (64 f32)
//   [8448, 82176)        A1: conv1 weights packed [c][mt][tap][kb][o32][8k] bf16 (4x18432)
//   [82176, 155904)      A2: conv2 weights packed
//   [155904, 37904640)   x_t: 4 planes of [b][h][w][ci16] bf16 (plane = 9,437,184 B)
//   [37904640, 75653376) f1t: 4 planes of [b][h][w][o16]  bf16
#define WS_XFS   0
#define WS_ZERO  8192
#define WS_A1    8448
#define WS_A2    82176
#define WS_XT    155904
#define WS_F1T   37904640
#define PLANE    9437184   // bytes per ci-chunk plane
#define ACHUNK   18432     // bytes per A chunk

__device__ __forceinline__ unsigned short b16(float f) {
    unsigned int u = __builtin_bit_cast(unsigned int, f);
    unsigned int r = (u + 0x7FFFu + ((u >> 16) & 1u)) >> 16;
    return (unsigned short)r;
}

__device__ __forceinline__ void gl_lds16(const void* g, void* l) {
    __builtin_amdgcn_global_load_lds(
        (const __attribute__((address_space(1))) unsigned int*)g,
        (__attribute__((address_space(3))) unsigned int*)l, 16, 0, 0);
}

// fused: A-pack for both convs (blocks 0..287) + zero xfs/zeropage (blocks 288+)
// A layout: chunk c (16 ci), granule ga = (mt*9+tap)*64 + kb*32 + ol ; elem j=0..7 -> ci = c*16+kb*8+j
__global__ void prep_small(const float* __restrict__ c1w, const float* __restrict__ c2w,
                           char* __restrict__ ws) {
    const int bid = blockIdx.x, tx = threadIdx.x;
    if (bid < 288) {
        const float* w = bid < 144 ? c1w : c2w;
        unsigned short* At = (unsigned short*)(ws + (bid < 144 ? WS_A1 : WS_A2));
        int idx = (bid % 144) * 256 + tx;        // 0..36863
        int j = idx & 7, ga_g = idx >> 3;        // granule id 0..4607
        int c = ga_g / 1152, gc = ga_g % 1152;
        int mtt = gc >> 6, kbol = gc & 63;
        int mt = mtt / 9, tap = mtt % 9;
        int kb = kbol >> 5, ol = kbol & 31;
        int o = mt * 32 + ol, ci = c * 16 + kb * 8 + j;
        At[idx] = b16(w[(o * 64 + ci) * 9 + tap]);
    } else {
        int i = (bid - 288) * 256 + tx;
        if (i < 2112) ((float*)ws)[i] = 0.f;     // xfs(2048) + zero page(64)
    }
}

// x[b][ci][h][w] f32 -> x_t chunk-planes; 2 pixels x 8 ci per thread
__global__ __launch_bounds__(256)
void prep_x(const float* __restrict__ x, char* __restrict__ xt) {
    int gid = blockIdx.x * 256 + threadIdx.x;   // 8 cig * 147456 pixel-pairs
    int cig = gid / 147456;
    int pp  = gid % 147456;
    int p   = pp * 2;
    int b   = p / 9216;
    int hw  = p % 9216;
    const float* src = x + (size_t)(b * 64 + cig * 8) * 9216 + hw;
    float2 v0 = *(const float2*)(src + 0 * 9216);
    float2 v1 = *(const float2*)(src + 1 * 9216);
    float2 v2 = *(const float2*)(src + 2 * 9216);
    float2 v3 = *(const float2*)(src + 3 * 9216);
    float2 v4 = *(const float2*)(src + 4 * 9216);
    float2 v5 = *(const float2*)(src + 5 * 9216);
    float2 v6 = *(const float2*)(src + 6 * 9216);
    float2 v7 = *(const float2*)(src + 7 * 9216);
    int c = cig >> 1, kb2 = cig & 1;
    char* dst = xt + (size_t)c * PLANE + (size_t)p * 32 + kb2 * 16;
    ushort4 a0, a1, c0, c1;
    a0.x = b16(v0.x); a0.y = b16(v1.x); a0.z = b16(v2.x); a0.w = b16(v3.x);
    a1.x = b16(v4.x); a1.y = b16(v5.x); a1.z = b16(v6.x); a1.w = b16(v7.x);
    c0.x = b16(v0.y); c0.y = b16(v1.y); c0.z = b16(v2.y); c0.w = b16(v3.y);
    c1.x = b16(v4.y); c1.y = b16(v5.y); c1.z = b16(v6.y); c1.w = b16(v7.y);
    *(ushort4*)(dst)      = a0; *(ushort4*)(dst + 8)  = a1;
    *(ushort4*)(dst + 32) = c0; *(ushort4*)(dst + 40) = c1;
}

// Implicit-GEMM conv + BN + ReLU, 2-phase pipelined.
// Block = 256 thr (4 waves) = 4 output rows x 96 cols x 64 och; wave = 1 row x 2 mt x 3 nt.
// LDS: ibuf0[18432] ibuf1[18432] abuf[18432] s_s/s_t. Input dbuf overlapped; A staged per chunk.
template <int POOL>
__global__ __launch_bounds__(256, 2)
void conv_mfma(const char* __restrict__ xt, const char* __restrict__ Aprep,
               const char* __restrict__ zerop,
               const float* __restrict__ gg, const float* __restrict__ bb,
               const float* __restrict__ mm, const float* __restrict__ vv_,
               char* __restrict__ f1t, float* __restrict__ xfs) {
    __shared__ char smem[55808];
    float* s_s = (float*)(smem + 55296);
    float* s_t = s_s + 64;

    const int tx = threadIdx.x;
    const int r0 = blockIdx.x * 4;
    const int b  = blockIdx.y;
    const int wv = tx >> 6, l = tx & 63;
    const int rh = wv;                    // output row within block
    const int kb = l >> 5, ln = l & 31;

    if (tx < 64) {
        float inv = rsqrtf(vv_[tx] + 1e-5f);
        s_s[tx] = gg[tx] * inv;
        s_t[tx] = bb[tx] - mm[tx] * gg[tx] * inv;
    }

    // ---- input staging sources: granule g = tx + 256*i, g < 1152 ----
    // g -> row(6) x kb2(2) x col(96); byte in tile = g*16
    const char* isrc[5];
    bool ioob[5];
#pragma unroll
    for (int i = 0; i < 5; ++i) {
        int g = i * 256 + tx;
        int row = g / 192, t = g % 192;
        int kb2 = t / 96, col = t % 96;
        int grow = r0 - 1 + row;
        ioob[i] = (grow < 0) || (grow >= 96) || (g >= 1152);
        int gr = (grow < 0 || grow >= 96) ? 0 : grow;
        isrc[i] = xt + (size_t)((b * 96 + gr) * 96 + col) * 32 + kb2 * 16;
    }
    // A staging source: linear
    const char* abase = Aprep + (size_t)tx * 16;

    // ---- B column offsets per (nt, dw): kb*1536 + col*16 (clamped; masked at use) ----
    int colpart[3][3];
#pragma unroll
    for (int nt = 0; nt < 3; ++nt)
#pragma unroll
        for (int dw = 0; dw < 3; ++dw) {
            int cc = nt * 32 + ln + dw - 1;
            int ccc = cc < 0 ? 0 : (cc > 95 ? 95 : cc);
            colpart[nt][dw] = kb * 1536 + ccc * 16;
        }
    const bool msk0 = (ln == 0), msk2 = (ln == 31);

    // ---- staging helpers ----
    // stage input chunk c into ibuf sel
    auto stage_input = [&](int c, int sel) {
#pragma unroll
        for (int i = 0; i < 5; ++i) {
            int g = i * 256 + tx;
            if (g < 1152) {   // waves 2,3 skip i==4 (wave-uniform)
                const char* s = ioob[i] ? zerop : (isrc[i] + (size_t)c * PLANE);
                gl_lds16(s, smem + sel * 18432 + (size_t)g * 16);
            }
        }
    };
    auto stage_a = [&](int c) {
#pragma unroll
        for (int i = 0; i < 5; ++i) {
            int g = i * 256 + tx;
            if (g < 1152)
                gl_lds16(abase + (size_t)c * ACHUNK + i * 4096, smem + 36864 + (size_t)g * 16);
        }
    };

    f32x16 acc[2][3] = {};

    // ---- prologue: stage chunk 0 (input + A) ----
    stage_input(0, 0);
    stage_a(0);
    asm volatile("s_waitcnt vmcnt(0)");
    __syncthreads();

#pragma unroll
    for (int c = 0; c < 4; ++c) {
        const int cur = c & 1;
        // issue next input chunk early (lands during compute)
        if (c < 3) stage_input(c + 1, cur ^ 1);

        // ---- compute chunk c ----
        const char* ib = smem + cur * 18432;
#pragma unroll
        for (int tap = 0; tap < 9; ++tap) {
            const int dh = tap / 3, dw = tap % 3;
            short8 a0 = *(const short8*)(smem + 36864 + (tap)     * 1024 + kb * 512 + ln * 16);
            short8 a1 = *(const short8*)(smem + 36864 + (9 + tap) * 1024 + kb * 512 + ln * 16);
            const char* brow = ib + (rh + dh) * 3072;
#pragma unroll
            for (int nt = 0; nt < 3; ++nt) {
                short8 bf = *(const short8*)(brow + colpart[nt][dw]);
                if (nt == 0 && dw == 0) bf = msk0 ? (short8){} : bf;
                if (nt == 2 && dw == 2) bf = msk2 ? (short8){} : bf;
                acc[0][nt] = __builtin_amdgcn_mfma_f32_32x32x16_bf16(a0, bf, acc[0][nt], 0, 0, 0);
                acc[1][nt] = __builtin_amdgcn_mfma_f32_32x32x16_bf16(a1, bf, acc[1][nt], 0, 0, 0);
            }
        }

        if (c < 3) {
            // input c+1 arrived; all waves done reading abuf(c)
            asm volatile("s_waitcnt vmcnt(0)");
            __syncthreads();
            // stage A chunk c+1 (exposed wait, small)
            stage_a(c + 1);
            asm volatile("s_waitcnt vmcnt(0)");
            __syncthreads();
        }
    }

    // ---- epilogue ----
    const int r = r0 + rh;
    if (POOL == 0) {
#pragma unroll
        for (int nt = 0; nt < 3; ++nt) {
            int p = (b * 96 + r) * 96 + nt * 32 + ln;
            char* pb = f1t + (size_t)p * 32 + kb * 8;
#pragma unroll
            for (int mt = 0; mt < 2; ++mt)
#pragma unroll
                for (int qh = 0; qh < 4; ++qh) {
                    const int ob = mt * 32 + 8 * qh + 4 * kb;
                    float y0 = fmaxf(fmaf(acc[mt][nt][qh * 4 + 0], s_s[ob + 0], s_t[ob + 0]), 0.f);
                    float y1 = fmaxf(fmaf(acc[mt][nt][qh * 4 + 1], s_s[ob + 1], s_t[ob + 1]), 0.f);
                    float y2 = fmaxf(fmaf(acc[mt][nt][qh * 4 + 2], s_s[ob + 2], s_t[ob + 2]), 0.f);
                    float y3 = fmaxf(fmaf(acc[mt][nt][qh * 4 + 3], s_s[ob + 3], s_t[ob + 3]), 0.f);
                    uint2 pk;
                    pk.x = (unsigned)b16(y0) | ((unsigned)b16(y1) << 16);
                    pk.y = (unsigned)b16(y2) | ((unsigned)b16(y3) << 16);
                    *(uint2*)(pb + (size_t)(mt * 2 + (qh >> 1)) * PLANE + (qh & 1) * 16) = pk;
                }
        }
    } else {
#pragma unroll
        for (int mt = 0; mt < 2; ++mt)
#pragma unroll
            for (int qh = 0; qh < 4; ++qh)
#pragma unroll
                for (int j = 0; j < 4; ++j) {
                    const int o = mt * 32 + 8 * qh + 4 * kb + j;
                    const float ss = s_s[o], tt = s_t[o];
                    float y = fmaxf(fmaf(acc[mt][0][qh * 4 + j], ss, tt), 0.f)
                            + fmaxf(fmaf(acc[mt][1][qh * 4 + j], ss, tt), 0.f)
                            + fmaxf(fmaf(acc[mt][2][qh * 4 + j], ss, tt), 0.f);
#pragma unroll
                    for (int off = 1; off < 32; off <<= 1) y += __shfl_xor(y, off, 64);
                    if (ln == 0) atomicAdd(&xfs[b * 64 + o], y);
                }
    }
}

// Fused head: x_feat -> MLP -> softmax/loss -> EMA ref_new -> weighted ref -> out
__global__ __launch_bounds__(1024)
void head_kernel(const float* __restrict__ xfs, const float* __restrict__ rx,
                 const int* __restrict__ ty_g,
                 const float* __restrict__ w1, const float* __restrict__ b1,
                 const float* __restrict__ w2, const float* __restrict__ b2,
                 const float* __restrict__ rproj, float* __restrict__ out) {
    __shared__ float xf[BATCH][64];
    __shared__ float hb[BATCH][128];
    __shared__ float lg[BATCH][NT];
    __shared__ float rnew[NT][64];
    __shared__ float rxs[BATCH * 64];
    __shared__ int   ty[BATCH];
    __shared__ float lossb[BATCH];

    const int tx = threadIdx.x;

    for (int i = tx; i < BATCH * 64; i += 1024) {
        xf[i >> 6][i & 63] = xfs[i] * (1.f / 9216.f);
        rxs[i] = rx[i];
    }
    if (tx < BATCH) ty[tx] = ty_g[tx];
    __syncthreads();

    {
        int idx = tx;
#pragma unroll
        for (int u = 0; u < 4; ++u, idx += 1024) {
            int bb_ = idx >> 7, j = idx & 127;
            float s = b1[j];
#pragma unroll 8
            for (int c = 0; c < 64; ++c) s = fmaf(xf[bb_][c], w1[c * 128 + j], s);
            hb[bb_][j] = fmaxf(s, 0.f);
        }
    }
    __syncthreads();

    {
        int idx = tx;
#pragma unroll
        for (int u = 0; u < 2; ++u, idx += 1024) {
            int bb_ = idx >> 6, t = idx & 63;
            float s = b2[t];
#pragma unroll 8
            for (int j = 0; j < 128; ++j) s = fmaf(hb[bb_][j], w2[j * 64 + t], s);
            lg[bb_][t] = s;
        }
    }
    __syncthreads();

    float (*tw)[NT] = (float (*)[NT])xf;
    if (tx < BATCH) {
        int b = tx;
        float mx = -1e30f;
        for (int t = 0; t < NT; ++t) mx = fmaxf(mx, lg[b][t]);
        float sum = 0.f;
        for (int t = 0; t < NT; ++t) sum += expf(lg[b][t] - mx);
        float inv = 1.f / sum;
        for (int t = 0; t < NT; ++t) tw[b][t] = expf(lg[b][t] - mx) * inv;
        lossb[b] = -(lg[b][ty[b]] - mx - logf(sum));
    }
    __syncthreads();

    for (int idx = tx; idx < NT * 64; idx += 1024) {
        int t = idx >> 6, c = idx & 63;
        float r = rproj[idx];
#pragma unroll 8
        for (int i = 0; i < BATCH; ++i)
            if (ty[i] == t) r = 0.99f * r + 0.01f * rxs[i * 64 + c];
        rnew[t][c] = r;
        out[2049 + idx] = r;
    }
    __syncthreads();

    for (int idx = tx; idx < BATCH * 64; idx += 1024) {
        int b = idx >> 6, c = idx & 63;
        float s = 0.f;
#pragma unroll 8
        for (int t = 0; t < NT; ++t) s = fmaf(tw[b][t], rnew[t][c], s);
        out[idx] = s + rxs[idx];
    }
    if (tx == 0) {
        float s = 0.f;
        for (int b = 0; b < BATCH; ++b) s += lossb[b];
        out[2048] = s * (1.f / 32.f);
    }
}

extern "C" void kernel_launch(void* const* d_in, const int* in_sizes, int n_in,
                              void* d_out, int out_size, void* d_ws, size_t ws_size,
                              hipStream_t stream) {
    const float* x    = (const float*)d_in[0];
    const float* rx   = (const float*)d_in[1];
    const int*   ty   = (const int*)d_in[2];
    const float* c1w  = (const float*)d_in[3];
    const float* bn1g = (const float*)d_in[4];
    const float* bn1b = (const float*)d_in[5];
    const float* bn1m = (const float*)d_in[6];
    const float* bn1v = (const float*)d_in[7];
    const float* c2w  = (const float*)d_in[8];
    const float* bn2g = (const float*)d_in[9];
    const float* bn2b = (const float*)d_in[10];
    const float* bn2m = (const float*)d_in[11];
    const float* bn2v = (const float*)d_in[12];
    const float* w1   = (const float*)d_in[13];
    const float* b1   = (const float*)d_in[14];
    const float* w2   = (const float*)d_in[15];
    const float* b2   = (const float*)d_in[16];
    const float* rpj  = (const float*)d_in[17];

    char* ws = (char*)d_ws;
    float* xfs = (float*)(ws + WS_XFS);
    char*  zp  = ws + WS_ZERO;
    char*  A1  = ws + WS_A1;
    char*  A2  = ws + WS_A2;
    char*  x_t = ws + WS_XT;
    char*  f1t = ws + WS_F1T;
    float* out = (float*)d_out;

    prep_small<<<297, 256, 0, stream>>>(c1w, c2w, ws);
    prep_x<<<4608, 256, 0, stream>>>(x, x_t);

    dim3 grid(24, 32);   // (4-row groups, batch)
    conv_mfma<0><<<grid, 256, 0, stream>>>(x_t, A1, zp, bn1g, bn1b, bn1m, bn1v, f1t, nullptr);
    conv_mfma<1><<<grid, 256, 0, stream>>>(f1t, A2, zp, bn2g, bn2b, bn2m, bn2v, nullptr, xfs);

    head_kernel<<<1, 1024, 0, stream>>>(xfs, rx, ty, w1, b1, w2, b2, rpj, out);
}